// Round 9
// baseline (11751.875 us; speedup 1.0000x reference)
//
#include <hip/hip_runtime.h>
#include <math.h>

#define DMODEL 512
#define SEQ    257
#define BATCH  64
#define ROWS   (BATCH * SEQ)   // 16448

// ---------------- cubic B-spline bases (NB=8, grid h=0.4 on [-1,1]) ----------
__device__ __forceinline__ void bspline8(float x, float bas[8]) {
    float g[12];
#pragma unroll
    for (int i = 0; i < 12; ++i) g[i] = (float)(i - 3) * 0.4f + (-1.0f);
    float b[11];
#pragma unroll
    for (int i = 0; i < 11; ++i) b[i] = (x >= g[i] && x < g[i + 1]) ? 1.0f : 0.0f;
#pragma unroll
    for (int j = 1; j <= 3; ++j) {
#pragma unroll
        for (int i = 0; i < 10; ++i) {
            if (i + j < 11) {
                float left  = (x - g[i]) / (g[i + j] - g[i]) * b[i];
                float right = (g[i + j + 1] - x) / (g[i + j + 1] - g[i + 1]) * b[i + 1];
                b[i] = left + right;
            }
        }
    }
#pragma unroll
    for (int q = 0; q < 8; ++q) bas[q] = b[q];
}

// ---------------- textbook 16x16 tiled GEMM: C = A[M,K] @ B[N,K]^T + bias (+R)
__global__ void gemm16(const float* A, const float* B, const float* bias,
                       const float* R, float* C, int M, int N, int K) {
    __shared__ float As[16][17];
    __shared__ float Bs[16][17];
    int bm = blockIdx.y * 16, bn = blockIdx.x * 16;
    int tx = threadIdx.x, ty = threadIdx.y;
    float acc = 0.0f;
    for (int k0 = 0; k0 < K; k0 += 16) {
        As[ty][tx] = A[(size_t)(bm + ty) * K + k0 + tx];
        Bs[ty][tx] = B[(size_t)(bn + ty) * K + k0 + tx];
        __syncthreads();
        for (int kk = 0; kk < 16; ++kk) acc += As[ty][kk] * Bs[tx][kk];
        __syncthreads();
    }
    int row = bm + ty, col = bn + tx;
    float v = acc + bias[col];
    if (R) v += R[(size_t)row * N + col];
    C[(size_t)row * N + col] = v;
}

// ---------------- assemble -----------------------------------------------------
__global__ __launch_bounds__(256) void assemble_el(const float* x1, const int* ids,
                                                   const float* mask_tok, const float* pos,
                                                   float* outp) {
    size_t gid = (size_t)blockIdx.x * 256 + threadIdx.x;
    if (gid >= (size_t)ROWS * DMODEL) return;
    int d = (int)(gid & 511);
    int row = (int)(gid >> 9);
    int b = row / SEQ, p = row % SEQ;
    float v;
    if (p == 0) {
        v = x1[(size_t)(b * 65) * DMODEL + d];
    } else {
        int i = ids[b * 256 + (p - 1)];
        v = (i < 64) ? x1[(size_t)(b * 65 + 1 + i) * DMODEL + d] : mask_tok[d];
    }
    outp[gid] = v + pos[(size_t)p * DMODEL + d];
}

// ---------------- LayerNorm ----------------------------------------------------
__global__ __launch_bounds__(256) void ln_block(const float* x, const float* g,
                                                const float* bt, float* y) {
    int row = blockIdx.x;
    int t = threadIdx.x;
    __shared__ float sbuf[256];
    const float* xr = x + (size_t)row * DMODEL;
    float a0 = xr[t], a1 = xr[t + 256];
    sbuf[t] = a0 + a1;
    __syncthreads();
    for (int s = 128; s > 0; s >>= 1) { if (t < s) sbuf[t] += sbuf[t + s]; __syncthreads(); }
    float mean = sbuf[0] * (1.0f / DMODEL);
    __syncthreads();
    float d0 = a0 - mean, d1 = a1 - mean;
    sbuf[t] = d0 * d0 + d1 * d1;
    __syncthreads();
    for (int s = 128; s > 0; s >>= 1) { if (t < s) sbuf[t] += sbuf[t + s]; __syncthreads(); }
    float inv = rsqrtf(sbuf[0] * (1.0f / DMODEL) + 1e-5f);
    float* yr = y + (size_t)row * DMODEL;
    yr[t]       = d0 * inv * g[t]       + bt[t];
    yr[t + 256] = d1 * inv * g[t + 256] + bt[t + 256];
}

// ---------------- attention (8 heads, hd=64) -----------------------------------
__global__ __launch_bounds__(256) void attn_naive(const float* qkv, float* o) {
    int gid = blockIdx.x * 256 + threadIdx.x;
    if (gid >= BATCH * 8 * SEQ) return;
    int q = gid % SEQ;
    int bh = gid / SEQ;
    int h = bh % 8, b = bh / 8;
    const float* base = qkv + (size_t)b * SEQ * 1536;
    const float* Q = base + (size_t)q * 1536 + h * 64;
    float m = -1e30f;
    for (int k = 0; k < SEQ; ++k) {
        const float* Krow = base + (size_t)k * 1536 + 512 + h * 64;
        float s = 0.0f;
#pragma unroll
        for (int d = 0; d < 64; ++d) s += Q[d] * Krow[d];
        m = fmaxf(m, s * 0.125f);
    }
    float acc[64];
#pragma unroll
    for (int d = 0; d < 64; ++d) acc[d] = 0.0f;
    float l = 0.0f;
    for (int k = 0; k < SEQ; ++k) {
        const float* Krow = base + (size_t)k * 1536 + 512 + h * 64;
        float s = 0.0f;
#pragma unroll
        for (int d = 0; d < 64; ++d) s += Q[d] * Krow[d];
        float e = __expf(s * 0.125f - m);
        l += e;
        const float* Vrow = base + (size_t)k * 1536 + 1024 + h * 64;
#pragma unroll
        for (int d = 0; d < 64; ++d) acc[d] += e * Vrow[d];
    }
    float inv = 1.0f / l;
    float* orow = o + (size_t)(b * SEQ + q) * DMODEL + h * 64;
#pragma unroll
    for (int d = 0; d < 64; ++d) orow[d] = acc[d] * inv;
}

// ---------------- KAN: build fused weight W9[o, f*9+r] -------------------------
// W9[o][f][0] = base[o,f]; W9[o][f][1+q] = spline[o,f,q] * scaler[o,f]
__global__ __launch_bounds__(256) void buildw9_k(const float* base, const float* spline,
                                                 const float* scaler, float* W9, int total) {
    int gid = blockIdx.x * 256 + threadIdx.x;   // total = OUTDIM*512
    if (gid >= total) return;
    float sc = scaler[gid];
    float* w = W9 + (size_t)gid * 9;
    w[0] = base[gid];
#pragma unroll
    for (int q = 0; q < 8; ++q) w[1 + q] = spline[(size_t)gid * 8 + q] * sc;
}

// ---------------- KAN: expand x -> 9 features per input ------------------------
// E9[r, f*9+0] = silu(x); E9[r, f*9+1+q] = bas_q(x)
__global__ __launch_bounds__(256) void expand9_k(const float* src, float* E9,
                                                 int row0, int nrows, int indim) {
    int gid = blockIdx.x * 256 + threadIdx.x;
    if (gid >= nrows * indim) return;
    int f = gid % indim;
    int r = gid / indim;
    float x = src[(size_t)(row0 + r) * indim + f];
    float sil = x / (1.0f + __expf(-x));
    float bas[8];
    bspline8(x, bas);
    float* e = E9 + (size_t)r * (indim * 9) + f * 9;
    e[0] = sil;
#pragma unroll
    for (int q = 0; q < 8; ++q) e[1 + q] = bas[q];
}

// ---------------- misc ---------------------------------------------------------
__global__ void zero_k(float* p, int n) {
    int i = blockIdx.x * 256 + threadIdx.x;
    if (i < n) p[i] = 0.0f;
}
__global__ __launch_bounds__(256) void drop_copy_k(const float* k2out, float* out) {
    size_t gid = (size_t)blockIdx.x * 256 + threadIdx.x;
    if (gid >= (size_t)ROWS * 256) return;
    int t = (int)(gid & 255);
    int row = (int)(gid >> 8);
    int b = row / SEQ, p = row % SEQ;
    if (p == 0) return;
    out[((size_t)b * 256 + (p - 1)) * 256 + t] = k2out[gid];
}
__global__ void fill_out_k(float* o, int n) {
    int i = blockIdx.x * 256 + threadIdx.x;
    if (i < n) o[i] = 333.0f;
}
__global__ void diag_host_k(float* o, float val) {
    if (threadIdx.x == 0 && blockIdx.x == 0) o[0] = val;
}

// ---------------- launcher ---------------------------------------------------
extern "C" void kernel_launch(void* const* d_in, const int* in_sizes, int n_in,
                              void* d_out, int out_size, void* d_ws, size_t ws_size,
                              hipStream_t stream) {
    const float* x      = (const float*)d_in[0];
    const int*   ids    = (const int*)d_in[1];
    const float* dec_w  = (const float*)d_in[2];
    const float* dec_b  = (const float*)d_in[3];
    const float* mask_t = (const float*)d_in[4];
    const float* pos    = (const float*)d_in[5];
    const float* ln1_g  = (const float*)d_in[6];
    const float* ln1_b  = (const float*)d_in[7];
    const float* in_w   = (const float*)d_in[8];
    const float* in_b   = (const float*)d_in[9];
    const float* out_w  = (const float*)d_in[10];
    const float* out_b  = (const float*)d_in[11];
    const float* ln2_g  = (const float*)d_in[12];
    const float* ln2_b  = (const float*)d_in[13];
    const float* k1_base = (const float*)d_in[14];
    const float* k1_spl  = (const float*)d_in[15];
    const float* k1_sc   = (const float*)d_in[16];
    const float* k2_base = (const float*)d_in[17];
    const float* k2_spl  = (const float*)d_in[18];
    const float* k2_sc   = (const float*)d_in[19];
    float* out = (float*)d_out;

    // ---- geometry verification (CORRECTED sizes: KAN hidden H = 512) ----
    static const int exp_sizes[20] = {
        1597440, 16384, 196608, 512, 512, 524800, 512, 512,
        786432, 1536, 262144, 512, 512, 512,
        262144, 2097152, 262144, 131072, 1048576, 131072
    };
    int bad = -1;
    if (n_in != 20) bad = 55;
    else {
        for (int i = 0; i < 20; ++i)
            if (in_sizes[i] != exp_sizes[i]) { bad = i; break; }
        if (bad < 0 && out_size != 4194304) bad = 56;
    }
    if (bad >= 0) {
        // bf16-safe diagnostic: exponent encodes which check failed
        fill_out_k<<<(out_size + 255) / 256, 256, 0, stream>>>(out, out_size);
        float code = ldexpf(1.0f, 30 + bad);
        diag_host_k<<<1, 64, 0, stream>>>(out, code);
        return;
    }

    // ---- workspace layout (floats; fits verified >= 44,368,384) ----
    float* ws = (float*)d_ws;
    float* xres  = ws;                        // 8,421,376 ; after LN2: W9a/W9b/zeros/k2out
    float* hbuf  = ws + 8421376;              // 8,421,376 ; LN1 out -> attn out -> h2(LN2)
    float* R3    = ws + 16842752;             // 25,264,128 ; x1 -> qkv -> E9chunk+kan1o
    float* x1    = R3;                        // 2,129,920
    float* qkv   = R3;                        // 25,264,128
    float* E9    = R3;                        // 2048*4608 = 9,437,184
    float* kan1o = R3 + 9437184;              // 16448*512 = 8,421,376
    float* W9a   = ws;                        // 512*4608  = 2,359,296
    float* W9b   = ws + 2359296;              // 256*4608  = 1,179,648
    float* zeros = ws + 3538944;              // 512
    float* k2out = ws + 3539456;              // 16448*256 = 4,210,688  (ends 7,750,144)
    float* h2    = hbuf;

    // 1. decoder embed projection: (4160,384)@(512,384)^T
    gemm16<<<dim3(512 / 16, 4160 / 16), dim3(16, 16), 0, stream>>>(
        x, dec_w, dec_b, nullptr, x1, 4160, 512, 384);
    // 2. splice + gather + pos embed -> xres
    assemble_el<<<(ROWS * DMODEL + 255) / 256, 256, 0, stream>>>(x1, ids, mask_t, pos, xres);
    // 3. LN1 -> hbuf
    ln_block<<<ROWS, 256, 0, stream>>>(xres, ln1_g, ln1_b, hbuf);
    // 4. QKV projection -> qkv (overwrites x1; x1 dead)
    gemm16<<<dim3(1536 / 16, ROWS / 16), dim3(16, 16), 0, stream>>>(
        hbuf, in_w, in_b, nullptr, qkv, ROWS, 1536, 512);
    // 5. attention -> hbuf
    attn_naive<<<(BATCH * 8 * SEQ + 255) / 256, 256, 0, stream>>>(qkv, hbuf);
    // 6. out-proj + residual -> xres
    gemm16<<<dim3(512 / 16, ROWS / 16), dim3(16, 16), 0, stream>>>(
        hbuf, out_w, out_b, xres, xres, ROWS, 512, 512);
    // 7. LN2 -> h2 (hbuf; hbuf's old contents dead)
    ln_block<<<ROWS, 256, 0, stream>>>(xres, ln2_g, ln2_b, h2);

    // 7.5 build fused KAN weights (xres region now dead)
    zero_k<<<2, 256, 0, stream>>>(zeros, 512);
    buildw9_k<<<(262144 + 255) / 256, 256, 0, stream>>>(k1_base, k1_spl, k1_sc, W9a, 262144);
    buildw9_k<<<(131072 + 255) / 256, 256, 0, stream>>>(k2_base, k2_spl, k2_sc, W9b, 131072);

    // 8. KAN1: (rows,512) -> (rows,512) via E9(rows,4608) @ W9a(512,4608)^T, chunked
    for (int r0 = 0; r0 < ROWS; r0 += 2048) {
        int m = (ROWS - r0 < 2048) ? (ROWS - r0) : 2048;   // 2048 or 64, both %16==0
        expand9_k<<<(m * 512 + 255) / 256, 256, 0, stream>>>(h2, E9, r0, m, 512);
        gemm16<<<dim3(512 / 16, m / 16), dim3(16, 16), 0, stream>>>(
            E9, W9a, zeros, nullptr, kan1o + (size_t)r0 * 512, m, 512, 4608);
    }
    // 9. KAN2: (rows,512) -> (rows,256), chunked
    for (int r0 = 0; r0 < ROWS; r0 += 2048) {
        int m = (ROWS - r0 < 2048) ? (ROWS - r0) : 2048;
        expand9_k<<<(m * 512 + 255) / 256, 256, 0, stream>>>(kan1o, E9, r0, m, 512);
        gemm16<<<dim3(256 / 16, m / 16), dim3(16, 16), 0, stream>>>(
            E9, W9b, zeros, nullptr, k2out + (size_t)r0 * 256, m, 256, 4608);
    }
    // 10. drop p==0 rows -> out
    drop_copy_k<<<(int)(((size_t)ROWS * 256 + 255) / 256), 256, 0, stream>>>(k2out, out);
    (void)ws_size;
}

// Round 10
// 3571.791 us; speedup vs baseline: 3.2902x; 3.2902x over previous
//
#include <hip/hip_runtime.h>
#include <hip/hip_bf16.h>
#include <math.h>

#define DMODEL 512
#define SEQ    257
#define BATCH  64
#define ROWS   (BATCH * SEQ)   // 16448
#define ROWSP  16512           // padded to multiple of 128

typedef unsigned short ushortT;
typedef __attribute__((ext_vector_type(8))) __bf16 bf16x8;
typedef __attribute__((ext_vector_type(4))) float f32x4;

// ---------------- cubic B-spline bases (NB=8, grid h=0.4 on [-1,1]) ----------
__device__ __forceinline__ void bspline8(float x, float bas[8]) {
    float g[12];
#pragma unroll
    for (int i = 0; i < 12; ++i) g[i] = (float)(i - 3) * 0.4f + (-1.0f);
    float b[11];
#pragma unroll
    for (int i = 0; i < 11; ++i) b[i] = (x >= g[i] && x < g[i + 1]) ? 1.0f : 0.0f;
#pragma unroll
    for (int j = 1; j <= 3; ++j) {
#pragma unroll
        for (int i = 0; i < 10; ++i) {
            if (i + j < 11) {
                float left  = (x - g[i]) / (g[i + j] - g[i]) * b[i];
                float right = (g[i + j + 1] - x) / (g[i + j + 1] - g[i + 1]) * b[i + 1];
                b[i] = left + right;
            }
        }
    }
#pragma unroll
    for (int q = 0; q < 8; ++q) bas[q] = b[q];
}

// ---------------- bf16 MFMA GEMM: C[M,N] = A[M,K] @ B[N,K]^T + bias (+R) -----
// A,B bf16 row-major K-contiguous; C f32. M%128==0, N%128==0, K%32==0.
// 256 thr = 4 waves in 2x2; wave does 64x64 via 4x4 grid of 16x16x32 MFMA.
__global__ __launch_bounds__(256) void gemm_mfma(
    const ushortT* __restrict__ A, const ushortT* __restrict__ B,
    const float* __restrict__ bias, const float* __restrict__ R,
    float* __restrict__ C, int M, int N, int K) {
    __shared__ __align__(16) ushortT As[128 * 32];
    __shared__ __align__(16) ushortT Bs[128 * 32];
    const int tid = threadIdx.x;
    const int wave = tid >> 6, lane = tid & 63;
    const int bm = blockIdx.y * 128, bn = blockIdx.x * 128;
    const int wm = (wave >> 1) * 64, wn = (wave & 1) * 64;
    const int srow = tid >> 2;          // 0..63
    const int scol = (tid & 3) * 8;     // 0,8,16,24
    const int mrow = lane & 15;
    const int kq = (lane >> 4) * 8;     // quad*8
    f32x4 acc[4][4];
#pragma unroll
    for (int i = 0; i < 4; ++i)
#pragma unroll
        for (int j = 0; j < 4; ++j) acc[i][j] = (f32x4){0.f, 0.f, 0.f, 0.f};

    const ushortT* Ab = A + (size_t)(bm + srow) * K + scol;
    const ushortT* Bb = B + (size_t)(bn + srow) * K + scol;
    const int ldsI = srow * 32 + scol;
    for (int k0 = 0; k0 < K; k0 += 32) {
        int4 a0 = *(const int4*)(Ab + k0);
        int4 a1 = *(const int4*)(Ab + k0 + (size_t)64 * K);
        int4 b0 = *(const int4*)(Bb + k0);
        int4 b1 = *(const int4*)(Bb + k0 + (size_t)64 * K);
        __syncthreads();
        *(int4*)&As[ldsI] = a0;
        *(int4*)&As[ldsI + 64 * 32] = a1;
        *(int4*)&Bs[ldsI] = b0;
        *(int4*)&Bs[ldsI + 64 * 32] = b1;
        __syncthreads();
        bf16x8 af[4], bf[4];
#pragma unroll
        for (int i = 0; i < 4; ++i) af[i] = *(const bf16x8*)&As[(wm + i * 16 + mrow) * 32 + kq];
#pragma unroll
        for (int j = 0; j < 4; ++j) bf[j] = *(const bf16x8*)&Bs[(wn + j * 16 + mrow) * 32 + kq];
#pragma unroll
        for (int i = 0; i < 4; ++i)
#pragma unroll
            for (int j = 0; j < 4; ++j)
                acc[i][j] = __builtin_amdgcn_mfma_f32_16x16x32_bf16(af[i], bf[j], acc[i][j], 0, 0, 0);
    }
    const int r0 = (lane >> 4) * 4;   // C/D: row=(lane>>4)*4+reg, col=lane&15 [m89]
    const int cn = lane & 15;
#pragma unroll
    for (int i = 0; i < 4; ++i) {
#pragma unroll
        for (int j = 0; j < 4; ++j) {
            int col = bn + wn + j * 16 + cn;
            float bv = bias[col];
#pragma unroll
            for (int r = 0; r < 4; ++r) {
                int row = bm + wm + i * 16 + r0 + r;
                size_t idx = (size_t)row * N + col;
                float v = acc[i][j][r] + bv;
                if (R) v += R[idx];
                C[idx] = v;
            }
        }
    }
}

// ---------------- f32 -> bf16 convert ----------------------------------------
__global__ __launch_bounds__(256) void cvt_bf16_k(const float* __restrict__ s,
                                                  __hip_bfloat16* __restrict__ d, int n) {
    int i = blockIdx.x * 256 + threadIdx.x;
    if (i < n) d[i] = __float2bfloat16(s[i]);
}

// ---------------- assemble ----------------------------------------------------
__global__ __launch_bounds__(256) void assemble_el(const float* x1, const int* ids,
                                                   const float* mask_tok, const float* pos,
                                                   float* outp) {
    size_t gid = (size_t)blockIdx.x * 256 + threadIdx.x;
    if (gid >= (size_t)ROWS * DMODEL) return;
    int d = (int)(gid & 511);
    int row = (int)(gid >> 9);
    int b = row / SEQ, p = row % SEQ;
    float v;
    if (p == 0) {
        v = x1[(size_t)(b * 65) * DMODEL + d];
    } else {
        int i = ids[b * 256 + (p - 1)];
        v = (i < 64) ? x1[(size_t)(b * 65 + 1 + i) * DMODEL + d] : mask_tok[d];
    }
    outp[gid] = v + pos[(size_t)p * DMODEL + d];
}

// ---------------- LayerNorm -> bf16 -------------------------------------------
__global__ __launch_bounds__(256) void ln_bf16(const float* x, const float* g,
                                               const float* bt, __hip_bfloat16* y) {
    int row = blockIdx.x;
    int t = threadIdx.x;
    __shared__ float sbuf[256];
    const float* xr = x + (size_t)row * DMODEL;
    float a0 = xr[t], a1 = xr[t + 256];
    sbuf[t] = a0 + a1;
    __syncthreads();
    for (int s = 128; s > 0; s >>= 1) { if (t < s) sbuf[t] += sbuf[t + s]; __syncthreads(); }
    float mean = sbuf[0] * (1.0f / DMODEL);
    __syncthreads();
    float d0 = a0 - mean, d1 = a1 - mean;
    sbuf[t] = d0 * d0 + d1 * d1;
    __syncthreads();
    for (int s = 128; s > 0; s >>= 1) { if (t < s) sbuf[t] += sbuf[t + s]; __syncthreads(); }
    float inv = rsqrtf(sbuf[0] * (1.0f / DMODEL) + 1e-5f);
    __hip_bfloat16* yr = y + (size_t)row * DMODEL;
    yr[t]       = __float2bfloat16(d0 * inv * g[t]       + bt[t]);
    yr[t + 256] = __float2bfloat16(d1 * inv * g[t + 256] + bt[t + 256]);
}

// ---------------- attention (validated R9 structure; bf16 out) -----------------
__global__ __launch_bounds__(256) void attn_naive(const float* qkv, __hip_bfloat16* o) {
    int gid = blockIdx.x * 256 + threadIdx.x;
    if (gid >= BATCH * 8 * SEQ) return;
    int q = gid % SEQ;
    int bh = gid / SEQ;
    int h = bh % 8, b = bh / 8;
    const float* base = qkv + (size_t)b * SEQ * 1536;
    const float* Q = base + (size_t)q * 1536 + h * 64;
    float m = -1e30f;
    for (int k = 0; k < SEQ; ++k) {
        const float* Krow = base + (size_t)k * 1536 + 512 + h * 64;
        float s = 0.0f;
#pragma unroll
        for (int d = 0; d < 64; ++d) s += Q[d] * Krow[d];
        m = fmaxf(m, s * 0.125f);
    }
    float acc[64];
#pragma unroll
    for (int d = 0; d < 64; ++d) acc[d] = 0.0f;
    float l = 0.0f;
    for (int k = 0; k < SEQ; ++k) {
        const float* Krow = base + (size_t)k * 1536 + 512 + h * 64;
        float s = 0.0f;
#pragma unroll
        for (int d = 0; d < 64; ++d) s += Q[d] * Krow[d];
        float e = __expf(s * 0.125f - m);
        l += e;
        const float* Vrow = base + (size_t)k * 1536 + 1024 + h * 64;
#pragma unroll
        for (int d = 0; d < 64; ++d) acc[d] += e * Vrow[d];
    }
    float inv = 1.0f / l;
    __hip_bfloat16* orow = o + (size_t)(b * SEQ + q) * DMODEL + h * 64;
#pragma unroll
    for (int d = 0; d < 64; ++d) orow[d] = __float2bfloat16(acc[d] * inv);
}

// ---------------- KAN fused weight (bf16) -------------------------------------
__global__ __launch_bounds__(256) void buildw9_bf16(const float* base, const float* spline,
                                                    const float* scaler,
                                                    __hip_bfloat16* W9, int total) {
    int gid = blockIdx.x * 256 + threadIdx.x;
    if (gid >= total) return;
    float sc = scaler[gid];
    __hip_bfloat16* w = W9 + (size_t)gid * 9;
    w[0] = __float2bfloat16(base[gid]);
#pragma unroll
    for (int q = 0; q < 8; ++q) w[1 + q] = __float2bfloat16(spline[(size_t)gid * 8 + q] * sc);
}

// ---------------- KAN expand: x -> 9 bf16 features per input -------------------
__global__ __launch_bounds__(256) void expand9_f32(const float* src, __hip_bfloat16* E9,
                                                   int row0, int nrows) {
    int gid = blockIdx.x * 256 + threadIdx.x;
    if (gid >= nrows * DMODEL) return;
    int f = gid % DMODEL;
    int r = gid / DMODEL;
    float x = src[(size_t)(row0 + r) * DMODEL + f];
    float sil = x / (1.0f + __expf(-x));
    float bas[8];
    bspline8(x, bas);
    __hip_bfloat16* e = E9 + (size_t)r * (DMODEL * 9) + f * 9;
    e[0] = __float2bfloat16(sil);
#pragma unroll
    for (int q = 0; q < 8; ++q) e[1 + q] = __float2bfloat16(bas[q]);
}
__global__ __launch_bounds__(256) void expand9_b16(const __hip_bfloat16* src, __hip_bfloat16* E9,
                                                   int row0, int nrows) {
    int gid = blockIdx.x * 256 + threadIdx.x;
    if (gid >= nrows * DMODEL) return;
    int f = gid % DMODEL;
    int r = gid / DMODEL;
    float x = __bfloat162float(src[(size_t)(row0 + r) * DMODEL + f]);
    float sil = x / (1.0f + __expf(-x));
    float bas[8];
    bspline8(x, bas);
    __hip_bfloat16* e = E9 + (size_t)r * (DMODEL * 9) + f * 9;
    e[0] = __float2bfloat16(sil);
#pragma unroll
    for (int q = 0; q < 8; ++q) e[1 + q] = __float2bfloat16(bas[q]);
}

// ---------------- misc ---------------------------------------------------------
__global__ void zero_k(float* p, int n) {
    int i = blockIdx.x * 256 + threadIdx.x;
    if (i < n) p[i] = 0.0f;
}
__global__ __launch_bounds__(256) void drop_copy_k(const float* k2out, float* out) {
    size_t gid = (size_t)blockIdx.x * 256 + threadIdx.x;
    if (gid >= (size_t)ROWS * 256) return;
    int t = (int)(gid & 255);
    int row = (int)(gid >> 8);
    int b = row / SEQ, p = row % SEQ;
    if (p == 0) return;
    out[((size_t)b * 256 + (p - 1)) * 256 + t] = k2out[gid];
}
__global__ void fill_out_k(float* o, int n) {
    int i = blockIdx.x * 256 + threadIdx.x;
    if (i < n) o[i] = 333.0f;
}
__global__ void diag_host_k(float* o, float val) {
    if (threadIdx.x == 0 && blockIdx.x == 0) o[0] = val;
}

// ---------------- launcher ---------------------------------------------------
extern "C" void kernel_launch(void* const* d_in, const int* in_sizes, int n_in,
                              void* d_out, int out_size, void* d_ws, size_t ws_size,
                              hipStream_t stream) {
    const float* x      = (const float*)d_in[0];
    const int*   ids    = (const int*)d_in[1];
    const float* dec_w  = (const float*)d_in[2];
    const float* dec_b  = (const float*)d_in[3];
    const float* mask_t = (const float*)d_in[4];
    const float* pos    = (const float*)d_in[5];
    const float* ln1_g  = (const float*)d_in[6];
    const float* ln1_b  = (const float*)d_in[7];
    const float* in_w   = (const float*)d_in[8];
    const float* in_b   = (const float*)d_in[9];
    const float* out_w  = (const float*)d_in[10];
    const float* out_b  = (const float*)d_in[11];
    const float* ln2_g  = (const float*)d_in[12];
    const float* ln2_b  = (const float*)d_in[13];
    const float* k1_base = (const float*)d_in[14];
    const float* k1_spl  = (const float*)d_in[15];
    const float* k1_sc   = (const float*)d_in[16];
    const float* k2_base = (const float*)d_in[17];
    const float* k2_spl  = (const float*)d_in[18];
    const float* k2_sc   = (const float*)d_in[19];
    float* out = (float*)d_out;

    // ---- geometry verification (validated in R9) ----
    static const int exp_sizes[20] = {
        1597440, 16384, 196608, 512, 512, 524800, 512, 512,
        786432, 1536, 262144, 512, 512, 512,
        262144, 2097152, 262144, 131072, 1048576, 131072
    };
    int bad = -1;
    if (n_in != 20) bad = 55;
    else {
        for (int i = 0; i < 20; ++i)
            if (in_sizes[i] != exp_sizes[i]) { bad = i; break; }
        if (bad < 0 && out_size != 4194304) bad = 56;
    }
    if (bad >= 0) {
        fill_out_k<<<(out_size + 255) / 256, 256, 0, stream>>>(out, out_size);
        diag_host_k<<<1, 64, 0, stream>>>(out, ldexpf(1.0f, 30 + bad));
        return;
    }

    // ---- workspace layout (float units; total 40,436,224 < 44,368,384 avail) ----
    float* ws = (float*)d_ws;
    float* xres  = ws;                                   // f32 [16512*512]
    __hip_bfloat16* hbufb = (__hip_bfloat16*)(ws + 8454144);   // bf16 [16512*512]
    float* Q     = ws + 12681216;                        // 25,362,432 f region
    float* x1    = Q;                                    // f32 [4224*512]
    __hip_bfloat16* xbf = (__hip_bfloat16*)(Q + 2162688);      // bf16 [4224*384]
    float* kan1o = Q;                                    // f32 [16512*512] (after attn)
    __hip_bfloat16* E9  = (__hip_bfloat16*)(Q + 8454144);      // bf16 [2048*4608]
    float* k2out = Q + 13172736;                         // f32 [16512*256]
    float* qkv   = Q;                                    // f32 [16512*1536]
    float* W     = ws + 38043648;
    __hip_bfloat16* dec_wb = (__hip_bfloat16*)(W);
    __hip_bfloat16* in_wb  = (__hip_bfloat16*)(W + 98304);
    __hip_bfloat16* out_wb = (__hip_bfloat16*)(W + 491520);
    __hip_bfloat16* W9a    = (__hip_bfloat16*)(W + 622592);
    __hip_bfloat16* W9b    = (__hip_bfloat16*)(W + 1802240);
    float* zeros = W + 2392064;

    // 0. one-time converts (weights + x) and zeros
    zero_k<<<2, 256, 0, stream>>>(zeros, 512);
    cvt_bf16_k<<<(1597440 + 255) / 256, 256, 0, stream>>>(x, xbf, 1597440);
    cvt_bf16_k<<<(196608 + 255) / 256, 256, 0, stream>>>(dec_w, dec_wb, 196608);
    cvt_bf16_k<<<(786432 + 255) / 256, 256, 0, stream>>>(in_w, in_wb, 786432);
    cvt_bf16_k<<<(262144 + 255) / 256, 256, 0, stream>>>(out_w, out_wb, 262144);
    buildw9_bf16<<<(262144 + 255) / 256, 256, 0, stream>>>(k1_base, k1_spl, k1_sc, W9a, 262144);
    buildw9_bf16<<<(131072 + 255) / 256, 256, 0, stream>>>(k2_base, k2_spl, k2_sc, W9b, 131072);

    // 1. decoder embed projection: (4224p,384)@(512,384)^T -> x1 f32
    gemm_mfma<<<dim3(4, 33), 256, 0, stream>>>(
        (const ushortT*)xbf, (const ushortT*)dec_wb, dec_b, nullptr, x1, 4224, 512, 384);
    // 2. splice + gather + pos embed -> xres
    assemble_el<<<(ROWS * DMODEL + 255) / 256, 256, 0, stream>>>(x1, ids, mask_t, pos, xres);
    // 3. LN1 -> hbufb (bf16)
    ln_bf16<<<ROWS, 256, 0, stream>>>(xres, ln1_g, ln1_b, hbufb);
    // 4. QKV: (16512p,512)@(1536,512)^T -> qkv f32 (x1/xbf dead)
    gemm_mfma<<<dim3(12, 129), 256, 0, stream>>>(
        (const ushortT*)hbufb, (const ushortT*)in_wb, in_b, nullptr, qkv, ROWSP, 1536, 512);
    // 5. attention -> hbufb (bf16)
    attn_naive<<<(BATCH * 8 * SEQ + 255) / 256, 256, 0, stream>>>(qkv, hbufb);
    // 6. out-proj + residual -> xres (qkv dead after this GEMM's A reads? A=hbufb; qkv dead now)
    gemm_mfma<<<dim3(4, 129), 256, 0, stream>>>(
        (const ushortT*)hbufb, (const ushortT*)out_wb, out_b, xres, xres, ROWSP, 512, 512);
    // 7. LN2 -> hbufb (bf16)
    ln_bf16<<<ROWS, 256, 0, stream>>>(xres, ln2_g, ln2_b, hbufb);

    // 8. KAN1: chunks of 2048 rows; E9(m,4608)bf16 @ W9a(512,4608)^T -> kan1o f32
    for (int r0 = 0; r0 < ROWS; r0 += 2048) {
        int m = (ROWS - r0 < 2048) ? (ROWS - r0) : 2048;
        int mp = (m + 127) / 128 * 128;
        expand9_b16<<<(m * DMODEL + 255) / 256, 256, 0, stream>>>(hbufb, E9, r0, m);
        gemm_mfma<<<dim3(4, mp / 128), 256, 0, stream>>>(
            (const ushortT*)E9, (const ushortT*)W9a, zeros, nullptr,
            kan1o + (size_t)r0 * 512, mp, 512, 4608);
    }
    // 9. KAN2: chunks; -> k2out f32
    for (int r0 = 0; r0 < ROWS; r0 += 2048) {
        int m = (ROWS - r0 < 2048) ? (ROWS - r0) : 2048;
        int mp = (m + 127) / 128 * 128;
        expand9_f32<<<(m * DMODEL + 255) / 256, 256, 0, stream>>>(kan1o, E9, r0, m);
        gemm_mfma<<<dim3(2, mp / 128), 256, 0, stream>>>(
            (const ushortT*)E9, (const ushortT*)W9b, zeros, nullptr,
            k2out + (size_t)r0 * 256, mp, 256, 4608);
    }
    // 10. drop p==0 rows -> out
    drop_copy_k<<<(int)(((size_t)ROWS * 256 + 255) / 256), 256, 0, stream>>>(k2out, out);
    (void)ws_size;
}

// Round 11
// 1980.102 us; speedup vs baseline: 5.9350x; 1.8038x over previous
//
#include <hip/hip_runtime.h>
#include <hip/hip_bf16.h>
#include <math.h>

#define DMODEL 512
#define SEQ    257
#define BATCH  64
#define ROWS   (BATCH * SEQ)   // 16448
#define ROWSP  16512           // padded to multiple of 128
#define SP     288             // padded key stride for attention LDS

typedef unsigned short ushortT;
typedef __attribute__((ext_vector_type(8))) __bf16 bf16x8;
typedef __attribute__((ext_vector_type(4))) float f32x4;

// ---------------- cubic B-spline bases (NB=8, grid h=0.4 on [-1,1]) ----------
__device__ __forceinline__ void bspline8(float x, float bas[8]) {
    float g[12];
#pragma unroll
    for (int i = 0; i < 12; ++i) g[i] = (float)(i - 3) * 0.4f + (-1.0f);
    float b[11];
#pragma unroll
    for (int i = 0; i < 11; ++i) b[i] = (x >= g[i] && x < g[i + 1]) ? 1.0f : 0.0f;
#pragma unroll
    for (int j = 1; j <= 3; ++j) {
#pragma unroll
        for (int i = 0; i < 10; ++i) {
            if (i + j < 11) {
                float left  = (x - g[i]) / (g[i + j] - g[i]) * b[i];
                float right = (g[i + j + 1] - x) / (g[i + j + 1] - g[i + 1]) * b[i + 1];
                b[i] = left + right;
            }
        }
    }
#pragma unroll
    for (int q = 0; q < 8; ++q) bas[q] = b[q];
}

__device__ __forceinline__ ushortT f2bf(float v) {
    __hip_bfloat16 t = __float2bfloat16(v);
    return *(ushortT*)&t;
}

// ---------------- bf16 MFMA GEMM: C[M,N] = A[M,K] @ B[N,K]^T + bias (+R) -----
__global__ __launch_bounds__(256) void gemm_mfma(
    const ushortT* __restrict__ A, const ushortT* __restrict__ B,
    const float* __restrict__ bias, const float* __restrict__ R,
    float* __restrict__ C, int M, int N, int K) {
    __shared__ __align__(16) ushortT As[128 * 32];
    __shared__ __align__(16) ushortT Bs[128 * 32];
    const int tid = threadIdx.x;
    const int wave = tid >> 6, lane = tid & 63;
    const int bm = blockIdx.y * 128, bn = blockIdx.x * 128;
    const int wm = (wave >> 1) * 64, wn = (wave & 1) * 64;
    const int srow = tid >> 2;
    const int scol = (tid & 3) * 8;
    const int mrow = lane & 15;
    const int kq = (lane >> 4) * 8;
    f32x4 acc[4][4];
#pragma unroll
    for (int i = 0; i < 4; ++i)
#pragma unroll
        for (int j = 0; j < 4; ++j) acc[i][j] = (f32x4){0.f, 0.f, 0.f, 0.f};

    const ushortT* Ab = A + (size_t)(bm + srow) * K + scol;
    const ushortT* Bb = B + (size_t)(bn + srow) * K + scol;
    const int ldsI = srow * 32 + scol;
    for (int k0 = 0; k0 < K; k0 += 32) {
        int4 a0 = *(const int4*)(Ab + k0);
        int4 a1 = *(const int4*)(Ab + k0 + (size_t)64 * K);
        int4 b0 = *(const int4*)(Bb + k0);
        int4 b1 = *(const int4*)(Bb + k0 + (size_t)64 * K);
        __syncthreads();
        *(int4*)&As[ldsI] = a0;
        *(int4*)&As[ldsI + 64 * 32] = a1;
        *(int4*)&Bs[ldsI] = b0;
        *(int4*)&Bs[ldsI + 64 * 32] = b1;
        __syncthreads();
        bf16x8 af[4], bf[4];
#pragma unroll
        for (int i = 0; i < 4; ++i) af[i] = *(const bf16x8*)&As[(wm + i * 16 + mrow) * 32 + kq];
#pragma unroll
        for (int j = 0; j < 4; ++j) bf[j] = *(const bf16x8*)&Bs[(wn + j * 16 + mrow) * 32 + kq];
#pragma unroll
        for (int i = 0; i < 4; ++i)
#pragma unroll
            for (int j = 0; j < 4; ++j)
                acc[i][j] = __builtin_amdgcn_mfma_f32_16x16x32_bf16(af[i], bf[j], acc[i][j], 0, 0, 0);
    }
    const int r0 = (lane >> 4) * 4;
    const int cn = lane & 15;
#pragma unroll
    for (int i = 0; i < 4; ++i) {
#pragma unroll
        for (int j = 0; j < 4; ++j) {
            int col = bn + wn + j * 16 + cn;
            float bv = bias[col];
#pragma unroll
            for (int r = 0; r < 4; ++r) {
                int row = bm + wm + i * 16 + r0 + r;
                size_t idx = (size_t)row * N + col;
                float v = acc[i][j][r] + bv;
                if (R) v += R[idx];
                C[idx] = v;
            }
        }
    }
}

// ---------------- MFMA flash attention: block = (b,h) x 32-query tile ---------
// qkv f32 rows (B*S,1536)=q|k|v ; out bf16 (B*S,512)
__global__ __launch_bounds__(128) void attn_mfma(const float* __restrict__ qkv,
                                                 __hip_bfloat16* __restrict__ o) {
    __shared__ __align__(16) ushortT Sc[32 * SP];   // scores/P bf16
    __shared__ __align__(16) ushortT KV[64 * SP];   // union: K[272*64] then Vt[64*288]
    __shared__ float Linv[32];
    const int bh = blockIdx.x;
    const int h = bh & 7, b = bh >> 3;
    const int q0 = blockIdx.y * 32;
    const int tid = threadIdx.x;
    const int wave = tid >> 6, lane = tid & 63;
    const int l15 = lane & 15;
    const int quad = lane >> 4;
    const float* base = qkv + (size_t)b * SEQ * 1536;

    // ---- stage 1: K -> LDS bf16 (rows 257..271 zero) ----
    for (int g = tid; g < 272 * 8; g += 128) {
        int k = g >> 3;
        int d0 = (g & 7) * 8;
        int4 pk;
        ushortT* pp = (ushortT*)&pk;
        if (k < SEQ) {
            const float* src = base + (size_t)k * 1536 + 512 + h * 64 + d0;
#pragma unroll
            for (int i = 0; i < 8; ++i) pp[i] = f2bf(src[i]);
        } else {
#pragma unroll
            for (int i = 0; i < 8; ++i) pp[i] = 0;
        }
        *(int4*)&KV[k * 64 + d0] = pk;
    }

    // ---- Q fragments (A-operand layout), pre-scaled by 1/8 ----
    int q = q0 + wave * 16 + l15;
    if (q > SEQ - 1) q = SEQ - 1;
    const float* Qp = base + (size_t)q * 1536 + h * 64 + quad * 8;
    bf16x8 qf[2];
#pragma unroll
    for (int c = 0; c < 2; ++c) {
        union { bf16x8 v8; ushortT u[8]; } r;
#pragma unroll
        for (int i = 0; i < 8; ++i) r.u[i] = f2bf(Qp[c * 32 + i] * 0.125f);
        qf[c] = r.v8;
    }
    __syncthreads();

    // ---- stage 2: S = Q K^T -> Sc (bf16) ----
    for (int kt = 0; kt < 17; ++kt) {
        f32x4 sacc = (f32x4){0.f, 0.f, 0.f, 0.f};
#pragma unroll
        for (int c = 0; c < 2; ++c) {
            bf16x8 kf = *(const bf16x8*)&KV[(kt * 16 + l15) * 64 + c * 32 + quad * 8];
            sacc = __builtin_amdgcn_mfma_f32_16x16x32_bf16(qf[c], kf, sacc, 0, 0, 0);
        }
#pragma unroll
        for (int r = 0; r < 4; ++r) {
            int row = wave * 16 + quad * 4 + r;     // query-within-block
            Sc[row * SP + kt * 16 + l15] = f2bf(sacc[r]);
        }
    }
    __syncthreads();

    // ---- stage 3: V^T -> LDS bf16 (overwrites K region) ----
    for (int g = tid; g < 272 * 8; g += 128) {
        int key = g >> 3;
        int d0 = (g & 7) * 8;
        if (key < SEQ) {
            const float* src = base + (size_t)key * 1536 + 1024 + h * 64 + d0;
#pragma unroll
            for (int i = 0; i < 8; ++i) KV[(d0 + i) * SP + key] = f2bf(src[i]);
        } else {
#pragma unroll
            for (int i = 0; i < 8; ++i) KV[(d0 + i) * SP + key] = 0;
        }
    }
    // zero Vt cols 272..287 (pad region)
    for (int g = tid; g < 64 * 16; g += 128) {
        int d = g >> 4;
        KV[d * SP + 272 + (g & 15)] = 0;
    }
    __syncthreads();

    // ---- stage 4: softmax over keys (f32, threads 0..31) ----
    if (tid < 32) {
        int row = tid;
        float m = -1e30f;
        for (int k = 0; k < SEQ; ++k) {
            float s = __bfloat162float(*(__hip_bfloat16*)&Sc[row * SP + k]);
            m = fmaxf(m, s);
        }
        float l = 0.f;
        for (int k = 0; k < SEQ; ++k) {
            float s = __bfloat162float(*(__hip_bfloat16*)&Sc[row * SP + k]);
            float e = __expf(s - m);
            l += e;
            Sc[row * SP + k] = f2bf(e);
        }
        for (int k = SEQ; k < SP; ++k) Sc[row * SP + k] = 0;
        Linv[row] = 1.0f / l;
    }
    __syncthreads();

    // ---- stage 5: O = P V ----
    f32x4 oacc[4];
#pragma unroll
    for (int nf = 0; nf < 4; ++nf) oacc[nf] = (f32x4){0.f, 0.f, 0.f, 0.f};
    for (int kc = 0; kc < 9; ++kc) {
        bf16x8 pf = *(const bf16x8*)&Sc[(wave * 16 + l15) * SP + kc * 32 + quad * 8];
#pragma unroll
        for (int nf = 0; nf < 4; ++nf) {
            bf16x8 vf = *(const bf16x8*)&KV[(nf * 16 + l15) * SP + kc * 32 + quad * 8];
            oacc[nf] = __builtin_amdgcn_mfma_f32_16x16x32_bf16(pf, vf, oacc[nf], 0, 0, 0);
        }
    }
    // ---- epilogue ----
#pragma unroll
    for (int nf = 0; nf < 4; ++nf) {
#pragma unroll
        for (int r = 0; r < 4; ++r) {
            int row = quad * 4 + r;
            int qq = q0 + wave * 16 + row;
            if (qq < SEQ) {
                float v = oacc[nf][r] * Linv[wave * 16 + row];
                o[(size_t)(b * SEQ + qq) * DMODEL + h * 64 + nf * 16 + l15] = __float2bfloat16(v);
            }
        }
    }
}

// ---------------- f32 -> bf16 convert ----------------------------------------
__global__ __launch_bounds__(256) void cvt_bf16_k(const float* __restrict__ s,
                                                  __hip_bfloat16* __restrict__ d, int n) {
    int i = blockIdx.x * 256 + threadIdx.x;
    if (i < n) d[i] = __float2bfloat16(s[i]);
}

// ---------------- assemble ----------------------------------------------------
__global__ __launch_bounds__(256) void assemble_el(const float* x1, const int* ids,
                                                   const float* mask_tok, const float* pos,
                                                   float* outp) {
    size_t gid = (size_t)blockIdx.x * 256 + threadIdx.x;
    if (gid >= (size_t)ROWS * DMODEL) return;
    int d = (int)(gid & 511);
    int row = (int)(gid >> 9);
    int b = row / SEQ, p = row % SEQ;
    float v;
    if (p == 0) {
        v = x1[(size_t)(b * 65) * DMODEL + d];
    } else {
        int i = ids[b * 256 + (p - 1)];
        v = (i < 64) ? x1[(size_t)(b * 65 + 1 + i) * DMODEL + d] : mask_tok[d];
    }
    outp[gid] = v + pos[(size_t)p * DMODEL + d];
}

// ---------------- LayerNorm -> bf16 -------------------------------------------
__global__ __launch_bounds__(256) void ln_bf16(const float* x, const float* g,
                                               const float* bt, __hip_bfloat16* y) {
    int row = blockIdx.x;
    int t = threadIdx.x;
    __shared__ float sbuf[256];
    const float* xr = x + (size_t)row * DMODEL;
    float a0 = xr[t], a1 = xr[t + 256];
    sbuf[t] = a0 + a1;
    __syncthreads();
    for (int s = 128; s > 0; s >>= 1) { if (t < s) sbuf[t] += sbuf[t + s]; __syncthreads(); }
    float mean = sbuf[0] * (1.0f / DMODEL);
    __syncthreads();
    float d0 = a0 - mean, d1 = a1 - mean;
    sbuf[t] = d0 * d0 + d1 * d1;
    __syncthreads();
    for (int s = 128; s > 0; s >>= 1) { if (t < s) sbuf[t] += sbuf[t + s]; __syncthreads(); }
    float inv = rsqrtf(sbuf[0] * (1.0f / DMODEL) + 1e-5f);
    __hip_bfloat16* yr = y + (size_t)row * DMODEL;
    yr[t]       = __float2bfloat16(d0 * inv * g[t]       + bt[t]);
    yr[t + 256] = __float2bfloat16(d1 * inv * g[t + 256] + bt[t + 256]);
}

// ---------------- LayerNorm -> f32 (in-place safe) -----------------------------
__global__ __launch_bounds__(256) void ln_f32(const float* x, const float* g,
                                              const float* bt, float* y) {
    int row = blockIdx.x;
    int t = threadIdx.x;
    __shared__ float sbuf[256];
    const float* xr = x + (size_t)row * DMODEL;
    float a0 = xr[t], a1 = xr[t + 256];
    sbuf[t] = a0 + a1;
    __syncthreads();
    for (int s = 128; s > 0; s >>= 1) { if (t < s) sbuf[t] += sbuf[t + s]; __syncthreads(); }
    float mean = sbuf[0] * (1.0f / DMODEL);
    __syncthreads();
    float d0 = a0 - mean, d1 = a1 - mean;
    sbuf[t] = d0 * d0 + d1 * d1;
    __syncthreads();
    for (int s = 128; s > 0; s >>= 1) { if (t < s) sbuf[t] += sbuf[t + s]; __syncthreads(); }
    float inv = rsqrtf(sbuf[0] * (1.0f / DMODEL) + 1e-5f);
    float* yr = y + (size_t)row * DMODEL;
    yr[t]       = d0 * inv * g[t]       + bt[t];
    yr[t + 256] = d1 * inv * g[t + 256] + bt[t + 256];
}

// ---------------- KAN fused weight (bf16) -------------------------------------
__global__ __launch_bounds__(256) void buildw9_bf16(const float* base, const float* spline,
                                                    const float* scaler,
                                                    __hip_bfloat16* W9, int total) {
    int gid = blockIdx.x * 256 + threadIdx.x;
    if (gid >= total) return;
    float sc = scaler[gid];
    __hip_bfloat16* w = W9 + (size_t)gid * 9;
    w[0] = __float2bfloat16(base[gid]);
#pragma unroll
    for (int q = 0; q < 8; ++q) w[1 + q] = __float2bfloat16(spline[(size_t)gid * 8 + q] * sc);
}

// ---------------- KAN expand: f32 x -> 9 bf16 features -------------------------
__global__ __launch_bounds__(256) void expand9_f32(const float* src, __hip_bfloat16* E9,
                                                   int row0, int nrows) {
    int gid = blockIdx.x * 256 + threadIdx.x;
    if (gid >= nrows * DMODEL) return;
    int f = gid % DMODEL;
    int r = gid / DMODEL;
    float x = src[(size_t)(row0 + r) * DMODEL + f];
    float sil = x / (1.0f + __expf(-x));
    float bas[8];
    bspline8(x, bas);
    __hip_bfloat16* e = E9 + (size_t)r * (DMODEL * 9) + f * 9;
    e[0] = __float2bfloat16(sil);
#pragma unroll
    for (int q = 0; q < 8; ++q) e[1 + q] = __float2bfloat16(bas[q]);
}

// ---------------- misc ---------------------------------------------------------
__global__ void zero_k(float* p, int n) {
    int i = blockIdx.x * 256 + threadIdx.x;
    if (i < n) p[i] = 0.0f;
}
__global__ __launch_bounds__(256) void drop_copy_k(const float* k2out, float* out) {
    size_t gid = (size_t)blockIdx.x * 256 + threadIdx.x;
    if (gid >= (size_t)ROWS * 256) return;
    int t = (int)(gid & 255);
    int row = (int)(gid >> 8);
    int b = row / SEQ, p = row % SEQ;
    if (p == 0) return;
    out[((size_t)b * 256 + (p - 1)) * 256 + t] = k2out[gid];
}
__global__ void fill_out_k(float* o, int n) {
    int i = blockIdx.x * 256 + threadIdx.x;
    if (i < n) o[i] = 333.0f;
}
__global__ void diag_host_k(float* o, float val) {
    if (threadIdx.x == 0 && blockIdx.x == 0) o[0] = val;
}

// ---------------- launcher ---------------------------------------------------
extern "C" void kernel_launch(void* const* d_in, const int* in_sizes, int n_in,
                              void* d_out, int out_size, void* d_ws, size_t ws_size,
                              hipStream_t stream) {
    const float* x      = (const float*)d_in[0];
    const int*   ids    = (const int*)d_in[1];
    const float* dec_w  = (const float*)d_in[2];
    const float* dec_b  = (const float*)d_in[3];
    const float* mask_t = (const float*)d_in[4];
    const float* pos    = (const float*)d_in[5];
    const float* ln1_g  = (const float*)d_in[6];
    const float* ln1_b  = (const float*)d_in[7];
    const float* in_w   = (const float*)d_in[8];
    const float* in_b   = (const float*)d_in[9];
    const float* out_w  = (const float*)d_in[10];
    const float* out_b  = (const float*)d_in[11];
    const float* ln2_g  = (const float*)d_in[12];
    const float* ln2_b  = (const float*)d_in[13];
    const float* k1_base = (const float*)d_in[14];
    const float* k1_spl  = (const float*)d_in[15];
    const float* k1_sc   = (const float*)d_in[16];
    const float* k2_base = (const float*)d_in[17];
    const float* k2_spl  = (const float*)d_in[18];
    const float* k2_sc   = (const float*)d_in[19];
    float* out = (float*)d_out;

    static const int exp_sizes[20] = {
        1597440, 16384, 196608, 512, 512, 524800, 512, 512,
        786432, 1536, 262144, 512, 512, 512,
        262144, 2097152, 262144, 131072, 1048576, 131072
    };
    int bad = -1;
    if (n_in != 20) bad = 55;
    else {
        for (int i = 0; i < 20; ++i)
            if (in_sizes[i] != exp_sizes[i]) { bad = i; break; }
        if (bad < 0 && out_size != 4194304) bad = 56;
    }
    if (bad >= 0) {
        fill_out_k<<<(out_size + 255) / 256, 256, 0, stream>>>(out, out_size);
        diag_host_k<<<1, 64, 0, stream>>>(out, ldexpf(1.0f, 30 + bad));
        return;
    }

    // ---- workspace layout ----
    float* ws = (float*)d_ws;
    float* xres  = ws;                                         // f32 [16512*512]
    __hip_bfloat16* hbufb = (__hip_bfloat16*)(ws + 8454144);   // bf16 [16512*512]
    float* Q     = ws + 12681216;                              // 25.36M-float region
    float* x1    = Q;                                          // f32 [4224*512]
    __hip_bfloat16* xbf = (__hip_bfloat16*)(Q + 2162688);      // bf16 [4224*384]
    float* qkv   = Q;                                          // f32 [16512*1536]
    float* kan1o = Q;                                          // f32 [16512*512] (post-attn)
    __hip_bfloat16* E9  = (__hip_bfloat16*)(Q + 8454144);      // bf16 [4096*4608]
    float* k2out = Q + 17891328;                               // f32 [16512*256]
    float* W     = ws + 38043648;
    __hip_bfloat16* dec_wb = (__hip_bfloat16*)(W);
    __hip_bfloat16* in_wb  = (__hip_bfloat16*)(W + 98304);
    __hip_bfloat16* out_wb = (__hip_bfloat16*)(W + 491520);
    __hip_bfloat16* W9a    = (__hip_bfloat16*)(W + 622592);
    __hip_bfloat16* W9b    = (__hip_bfloat16*)(W + 1802240);
    float* zeros = W + 2392064;

    // 0. one-time converts + zeros
    zero_k<<<2, 256, 0, stream>>>(zeros, 512);
    cvt_bf16_k<<<(1597440 + 255) / 256, 256, 0, stream>>>(x, xbf, 1597440);
    cvt_bf16_k<<<(196608 + 255) / 256, 256, 0, stream>>>(dec_w, dec_wb, 196608);
    cvt_bf16_k<<<(786432 + 255) / 256, 256, 0, stream>>>(in_w, in_wb, 786432);
    cvt_bf16_k<<<(262144 + 255) / 256, 256, 0, stream>>>(out_w, out_wb, 262144);
    buildw9_bf16<<<(262144 + 255) / 256, 256, 0, stream>>>(k1_base, k1_spl, k1_sc, W9a, 262144);
    buildw9_bf16<<<(131072 + 255) / 256, 256, 0, stream>>>(k2_base, k2_spl, k2_sc, W9b, 131072);

    // 1. decoder embed projection
    gemm_mfma<<<dim3(4, 33), 256, 0, stream>>>(
        (const ushortT*)xbf, (const ushortT*)dec_wb, dec_b, nullptr, x1, 4224, 512, 384);
    // 2. splice + gather + pos embed -> xres
    assemble_el<<<(ROWS * DMODEL + 255) / 256, 256, 0, stream>>>(x1, ids, mask_t, pos, xres);
    // 3. LN1 -> hbufb (bf16)
    ln_bf16<<<ROWS, 256, 0, stream>>>(xres, ln1_g, ln1_b, hbufb);
    // 4. QKV -> qkv f32
    gemm_mfma<<<dim3(12, 129), 256, 0, stream>>>(
        (const ushortT*)hbufb, (const ushortT*)in_wb, in_b, nullptr, qkv, ROWSP, 1536, 512);
    // 5. MFMA flash attention -> hbufb (bf16)
    attn_mfma<<<dim3(BATCH * 8, 9), 128, 0, stream>>>(qkv, hbufb);
    // 6. out-proj + residual -> xres
    gemm_mfma<<<dim3(4, 129), 256, 0, stream>>>(
        (const ushortT*)hbufb, (const ushortT*)out_wb, out_b, xres, xres, ROWSP, 512, 512);
    // 7. LN2 -> xres f32 IN-PLACE (keeps spline input full-precision)
    ln_f32<<<ROWS, 256, 0, stream>>>(xres, ln2_g, ln2_b, xres);

    // 8. KAN1: chunks of 4096 rows
    for (int r0 = 0; r0 < ROWS; r0 += 4096) {
        int m = (ROWS - r0 < 4096) ? (ROWS - r0) : 4096;
        int mp = (m + 127) / 128 * 128;
        expand9_f32<<<(m * DMODEL + 255) / 256, 256, 0, stream>>>(xres, E9, r0, m);
        gemm_mfma<<<dim3(4, mp / 128), 256, 0, stream>>>(
            (const ushortT*)E9, (const ushortT*)W9a, zeros, nullptr,
            kan1o + (size_t)r0 * 512, mp, 512, 4608);
    }
    // 9. KAN2: chunks of 4096 rows
    for (int r0 = 0; r0 < ROWS; r0 += 4096) {
        int m = (ROWS - r0 < 4096) ? (ROWS - r0) : 4096;
        int mp = (m + 127) / 128 * 128;
        expand9_f32<<<(m * DMODEL + 255) / 256, 256, 0, stream>>>(kan1o, E9, r0, m);
        gemm_mfma<<<dim3(2, mp / 128), 256, 0, stream>>>(
            (const ushortT*)E9, (const ushortT*)W9b, zeros, nullptr,
            k2out + (size_t)r0 * 256, mp, 256, 4608);
    }
    // 10. drop p==0 rows -> out
    drop_copy_k<<<(int)(((size_t)ROWS * 256 + 255) / 256), 256, 0, stream>>>(k2out, out);
    (void)ws_size;
}

// Round 12
// 1444.013 us; speedup vs baseline: 8.1383x; 1.3712x over previous
//
#include <hip/hip_runtime.h>
#include <hip/hip_bf16.h>
#include <math.h>

#define DMODEL 512
#define SEQ    257
#define BATCH  64
#define ROWS   (BATCH * SEQ)   // 16448
#define ROWSP  16512

typedef unsigned short ushortT;
typedef __attribute__((ext_vector_type(8))) __bf16 bf16x8;
typedef __attribute__((ext_vector_type(4))) float f32x4;

__device__ __forceinline__ ushortT f2bf(float v) {
    __hip_bfloat16 t = __float2bfloat16(v);
    return *(ushortT*)&t;
}

// async 16B global->LDS (wave-uniform LDS base + lane*16)
__device__ __forceinline__ void gl16(const ushortT* g, ushortT* l) {
    __builtin_amdgcn_global_load_lds(
        (const __attribute__((address_space(1))) void*)g,
        (__attribute__((address_space(3))) void*)l, 16, 0, 0);
}

// ---------------- cubic B-spline bases -----------------------------------------
__device__ __forceinline__ void bspline8(float x, float bas[8]) {
    float g[12];
#pragma unroll
    for (int i = 0; i < 12; ++i) g[i] = (float)(i - 3) * 0.4f + (-1.0f);
    float b[11];
#pragma unroll
    for (int i = 0; i < 11; ++i) b[i] = (x >= g[i] && x < g[i + 1]) ? 1.0f : 0.0f;
#pragma unroll
    for (int j = 1; j <= 3; ++j) {
#pragma unroll
        for (int i = 0; i < 10; ++i) {
            if (i + j < 11) {
                float left  = (x - g[i]) / (g[i + j] - g[i]) * b[i];
                float right = (g[i + j + 1] - x) / (g[i + j + 1] - g[i + 1]) * b[i + 1];
                b[i] = left + right;
            }
        }
    }
#pragma unroll
    for (int q = 0; q < 8; ++q) bas[q] = b[q];
}

// ---------------- bf16 MFMA GEMM (global_load_lds staging) ---------------------
// C[M,N] = A[M,K] @ B[N,K]^T + bias (+R if OBF==0). OBF=1 -> bf16 C.
template<int OBF>
__global__ __launch_bounds__(256) void gemm_t(
    const ushortT* __restrict__ A, const ushortT* __restrict__ B,
    const float* __restrict__ bias, const float* __restrict__ R,
    void* __restrict__ Cv, int M, int N, int K) {
    __shared__ __align__(16) ushortT As[128 * 32];
    __shared__ __align__(16) ushortT Bs[128 * 32];
    const int tid = threadIdx.x;
    const int wave = tid >> 6, lane = tid & 63;
    const int bm = blockIdx.y * 128, bn = blockIdx.x * 128;
    const int wm = (wave >> 1) * 64, wn = (wave & 1) * 64;
    const int srow = tid >> 2;
    const int scol = (tid & 3) * 8;
    const int mrow = lane & 15;
    const int kq = (lane >> 4) * 8;
    f32x4 acc[4][4];
#pragma unroll
    for (int i = 0; i < 4; ++i)
#pragma unroll
        for (int j = 0; j < 4; ++j) acc[i][j] = (f32x4){0.f, 0.f, 0.f, 0.f};

    const ushortT* Ab = A + (size_t)(bm + srow) * K + scol;
    const ushortT* Bb = B + (size_t)(bn + srow) * K + scol;
    ushortT* AsW = As + wave * 512;
    ushortT* BsW = Bs + wave * 512;
    for (int k0 = 0; k0 < K; k0 += 32) {
        __syncthreads();
        gl16(Ab + k0, AsW);
        gl16(Ab + k0 + (size_t)64 * K, AsW + 2048);
        gl16(Bb + k0, BsW);
        gl16(Bb + k0 + (size_t)64 * K, BsW + 2048);
        __syncthreads();
        bf16x8 af[4], bf[4];
#pragma unroll
        for (int i = 0; i < 4; ++i) af[i] = *(const bf16x8*)&As[(wm + i * 16 + mrow) * 32 + kq];
#pragma unroll
        for (int j = 0; j < 4; ++j) bf[j] = *(const bf16x8*)&Bs[(wn + j * 16 + mrow) * 32 + kq];
#pragma unroll
        for (int i = 0; i < 4; ++i)
#pragma unroll
            for (int j = 0; j < 4; ++j)
                acc[i][j] = __builtin_amdgcn_mfma_f32_16x16x32_bf16(af[i], bf[j], acc[i][j], 0, 0, 0);
    }
    const int r0 = (lane >> 4) * 4;
    const int cn = lane & 15;
#pragma unroll
    for (int i = 0; i < 4; ++i) {
#pragma unroll
        for (int j = 0; j < 4; ++j) {
            int col = bn + wn + j * 16 + cn;
            float bv = bias[col];
#pragma unroll
            for (int r = 0; r < 4; ++r) {
                int row = bm + wm + i * 16 + r0 + r;
                size_t idx = (size_t)row * N + col;
                float v = acc[i][j][r] + bv;
                if (OBF) {
                    ((__hip_bfloat16*)Cv)[idx] = __float2bfloat16(v);
                } else {
                    if (R) v += R[idx];
                    ((float*)Cv)[idx] = v;
                }
            }
        }
    }
}

// ---------------- attention v2: bf16 qkv, swizzled Vt, parallel softmax --------
// grid (9 qtiles, 512 bh); block 128 (2 waves)
__global__ __launch_bounds__(128) void attn_mf2(const ushortT* __restrict__ qkvb,
                                                __hip_bfloat16* __restrict__ o) {
    __shared__ __align__(16) ushortT KV[64 * 320];  // K view [272][64] / Vt view [64][320]
    __shared__ __align__(16) ushortT Sc[32 * 288];
    __shared__ float Linv[32];
    const int q0 = blockIdx.x * 32;
    const int bh = blockIdx.y;
    const int h = bh & 7, b = bh >> 3;
    const int tid = threadIdx.x;
    const int wave = tid >> 6, lane = tid & 63;
    const int l15 = lane & 15;
    const int quad = lane >> 4;
    const size_t base = (size_t)(b * SEQ) * 1536;

    // stage K (bf16 copy, rows >= SEQ zero)
    for (int g = tid; g < 272 * 8; g += 128) {
        int k = g >> 3;
        int d0 = (g & 7) * 8;
        int4 v;
        if (k < SEQ) v = *(const int4*)&qkvb[base + (size_t)k * 1536 + 512 + h * 64 + d0];
        else v = (int4){0, 0, 0, 0};
        *(int4*)&KV[k * 64 + d0] = v;
    }
    // Q fragments, exact *0.125 (power of 2)
    int q = q0 + wave * 16 + l15;
    if (q > SEQ - 1) q = SEQ - 1;
    bf16x8 qf[2];
#pragma unroll
    for (int c = 0; c < 2; ++c) {
        union { bf16x8 v8; ushortT u[8]; } r;
        r.v8 = *(const bf16x8*)&qkvb[base + (size_t)q * 1536 + h * 64 + quad * 8 + c * 32];
#pragma unroll
        for (int i = 0; i < 8; ++i)
            r.u[i] = f2bf(__bfloat162float(*(__hip_bfloat16*)&r.u[i]) * 0.125f);
        qf[c] = r.v8;
    }
    __syncthreads();

    // S = (Q/8) K^T -> Sc bf16
    for (int kt = 0; kt < 17; ++kt) {
        f32x4 sacc = (f32x4){0.f, 0.f, 0.f, 0.f};
#pragma unroll
        for (int c = 0; c < 2; ++c) {
            bf16x8 kf = *(const bf16x8*)&KV[(kt * 16 + l15) * 64 + c * 32 + quad * 8];
            sacc = __builtin_amdgcn_mfma_f32_16x16x32_bf16(qf[c], kf, sacc, 0, 0, 0);
        }
#pragma unroll
        for (int r = 0; r < 4; ++r)
            Sc[(wave * 16 + quad * 4 + r) * 288 + kt * 16 + l15] = f2bf(sacc[r]);
    }
    __syncthreads();   // all S reads of K done; Sc fully written

    // stage Vt with XOR swizzle: addr(d,key) = d*320 + (key ^ ((d>>3)*8))
    for (int g = tid; g < 288 * 8; g += 128) {
        int key = g >> 3;
        int d0 = (g & 7) * 8;           // also the swizzle mask for d in [d0,d0+8)
        ushortT tmp[8];
        if (key < SEQ) {
            int4 v = *(const int4*)&qkvb[base + (size_t)key * 1536 + 1024 + h * 64 + d0];
            *(int4*)tmp = v;
        } else {
#pragma unroll
            for (int i = 0; i < 8; ++i) tmp[i] = 0;
        }
        int sk = key ^ d0;
#pragma unroll
        for (int i = 0; i < 8; ++i) KV[(d0 + i) * 320 + sk] = tmp[i];
    }
    // parallel softmax: 4 threads per row (intra-wave shfl)
    {
        int row = tid >> 2;             // 0..31 (wave-local rows)
        int stripe = tid & 3;
        float m = -1e30f;
        for (int k = stripe; k < SEQ; k += 4)
            m = fmaxf(m, __bfloat162float(*(__hip_bfloat16*)&Sc[row * 288 + k]));
        m = fmaxf(m, __shfl_xor(m, 1, 64));
        m = fmaxf(m, __shfl_xor(m, 2, 64));
        float l = 0.f;
        for (int k = stripe; k < SEQ; k += 4) {
            float s = __bfloat162float(*(__hip_bfloat16*)&Sc[row * 288 + k]);
            float e = __expf(s - m);
            l += e;
            Sc[row * 288 + k] = f2bf(e);
        }
        l += __shfl_xor(l, 1, 64);
        l += __shfl_xor(l, 2, 64);
        for (int k = SEQ + stripe; k < 288; k += 4) Sc[row * 288 + k] = 0;
        if (stripe == 0) Linv[row] = 1.0f / l;
    }
    __syncthreads();

    // O = P V
    f32x4 oacc[4];
#pragma unroll
    for (int nf = 0; nf < 4; ++nf) oacc[nf] = (f32x4){0.f, 0.f, 0.f, 0.f};
    for (int kc = 0; kc < 9; ++kc) {
        bf16x8 pf = *(const bf16x8*)&Sc[(wave * 16 + l15) * 288 + kc * 32 + quad * 8];
#pragma unroll
        for (int nf = 0; nf < 4; ++nf) {
            int d = nf * 16 + l15;
            int mask = ((d >> 3) & 7) * 8;
            bf16x8 vf = *(const bf16x8*)&KV[d * 320 + ((kc * 32 + quad * 8) ^ mask)];
            oacc[nf] = __builtin_amdgcn_mfma_f32_16x16x32_bf16(pf, vf, oacc[nf], 0, 0, 0);
        }
    }
#pragma unroll
    for (int nf = 0; nf < 4; ++nf) {
#pragma unroll
        for (int r = 0; r < 4; ++r) {
            int rr = quad * 4 + r;
            int qq = q0 + wave * 16 + rr;
            if (qq < SEQ)
                o[(size_t)(b * SEQ + qq) * DMODEL + h * 64 + nf * 16 + l15] =
                    __float2bfloat16(oacc[nf][r] * Linv[wave * 16 + rr]);
        }
    }
}

// ---------------- small kernels -------------------------------------------------
__global__ __launch_bounds__(256) void cvt_bf16_k(const float* __restrict__ s,
                                                  __hip_bfloat16* __restrict__ d, int n) {
    int i = blockIdx.x * 256 + threadIdx.x;
    if (i < n) d[i] = __float2bfloat16(s[i]);
}

__global__ __launch_bounds__(256) void assemble_el(const float* x1, const int* ids,
                                                   const float* mask_tok, const float* pos,
                                                   float* outp) {
    size_t gid = (size_t)blockIdx.x * 256 + threadIdx.x;
    if (gid >= (size_t)ROWS * DMODEL) return;
    int d = (int)(gid & 511);
    int row = (int)(gid >> 9);
    int b = row / SEQ, p = row % SEQ;
    float v;
    if (p == 0) {
        v = x1[(size_t)(b * 65) * DMODEL + d];
    } else {
        int i = ids[b * 256 + (p - 1)];
        v = (i < 64) ? x1[(size_t)(b * 65 + 1 + i) * DMODEL + d] : mask_tok[d];
    }
    outp[gid] = v + pos[(size_t)p * DMODEL + d];
}

__global__ __launch_bounds__(256) void ln_bf16(const float* x, const float* g,
                                               const float* bt, __hip_bfloat16* y) {
    int row = blockIdx.x;
    int t = threadIdx.x;
    __shared__ float sbuf[256];
    const float* xr = x + (size_t)row * DMODEL;
    float a0 = xr[t], a1 = xr[t + 256];
    sbuf[t] = a0 + a1;
    __syncthreads();
    for (int s = 128; s > 0; s >>= 1) { if (t < s) sbuf[t] += sbuf[t + s]; __syncthreads(); }
    float mean = sbuf[0] * (1.0f / DMODEL);
    __syncthreads();
    float d0 = a0 - mean, d1 = a1 - mean;
    sbuf[t] = d0 * d0 + d1 * d1;
    __syncthreads();
    for (int s = 128; s > 0; s >>= 1) { if (t < s) sbuf[t] += sbuf[t + s]; __syncthreads(); }
    float inv = rsqrtf(sbuf[0] * (1.0f / DMODEL) + 1e-5f);
    __hip_bfloat16* yr = y + (size_t)row * DMODEL;
    yr[t]       = __float2bfloat16(d0 * inv * g[t]       + bt[t]);
    yr[t + 256] = __float2bfloat16(d1 * inv * g[t + 256] + bt[t + 256]);
}

__global__ __launch_bounds__(256) void ln_f32(const float* x, const float* g,
                                              const float* bt, float* y) {
    int row = blockIdx.x;
    int t = threadIdx.x;
    __shared__ float sbuf[256];
    const float* xr = x + (size_t)row * DMODEL;
    float a0 = xr[t], a1 = xr[t + 256];
    sbuf[t] = a0 + a1;
    __syncthreads();
    for (int s = 128; s > 0; s >>= 1) { if (t < s) sbuf[t] += sbuf[t + s]; __syncthreads(); }
    float mean = sbuf[0] * (1.0f / DMODEL);
    __syncthreads();
    float d0 = a0 - mean, d1 = a1 - mean;
    sbuf[t] = d0 * d0 + d1 * d1;
    __syncthreads();
    for (int s = 128; s > 0; s >>= 1) { if (t < s) sbuf[t] += sbuf[t + s]; __syncthreads(); }
    float inv = rsqrtf(sbuf[0] * (1.0f / DMODEL) + 1e-5f);
    float* yr = y + (size_t)row * DMODEL;
    yr[t]       = d0 * inv * g[t]       + bt[t];
    yr[t + 256] = d1 * inv * g[t + 256] + bt[t + 256];
}

// W9 plane layout: W9[o*4608 + plane*512 + f], plane 0 = base, 1+q = spline*scaler
__global__ __launch_bounds__(256) void buildw9p(const float* base, const float* spline,
                                                const float* scaler, ushortT* W9, int total) {
    int gid = blockIdx.x * 256 + threadIdx.x;
    if (gid >= total) return;
    int f = gid & 511;
    int o = gid >> 9;
    size_t w = (size_t)o * 4608;
    W9[w + f] = f2bf(base[gid]);
    float sc = scaler[gid];
#pragma unroll
    for (int q = 0; q < 8; ++q)
        W9[w + (size_t)(1 + q) * 512 + f] = f2bf(spline[(size_t)gid * 8 + q] * sc);
}

// E9 plane layout: E9[r*4608 + plane*512 + f]; coalesced 16B stores per plane
__global__ __launch_bounds__(256) void expand9p(const float* src, ushortT* E9,
                                                int row0, int nrows) {
    int gid = blockIdx.x * 256 + threadIdx.x;
    if (gid >= nrows * 64) return;
    int f8 = gid & 63;
    int r = gid >> 6;
    const float* xr = src + (size_t)(row0 + r) * DMODEL + f8 * 8;
    ushortT pl[9][8];
#pragma unroll
    for (int j = 0; j < 8; ++j) {
        float x = xr[j];
        pl[0][j] = f2bf(x / (1.0f + __expf(-x)));
        float bas[8];
        bspline8(x, bas);
#pragma unroll
        for (int q = 0; q < 8; ++q) pl[1 + q][j] = f2bf(bas[q]);
    }
    ushortT* e = E9 + (size_t)r * 4608 + f8 * 8;
#pragma unroll
    for (int p = 0; p < 9; ++p) *(int4*)&e[(size_t)p * 512] = *(int4*)pl[p];
}

__global__ void zero_k(float* p, int n) {
    int i = blockIdx.x * 256 + threadIdx.x;
    if (i < n) p[i] = 0.0f;
}
__global__ __launch_bounds__(256) void drop_copy_k(const float* k2out, float* out) {
    size_t gid = (size_t)blockIdx.x * 256 + threadIdx.x;
    if (gid >= (size_t)ROWS * 256) return;
    int t = (int)(gid & 255);
    int row = (int)(gid >> 8);
    int b = row / SEQ, p = row % SEQ;
    if (p == 0) return;
    out[((size_t)b * 256 + (p - 1)) * 256 + t] = k2out[gid];
}
__global__ void fill_out_k(float* o, int n) {
    int i = blockIdx.x * 256 + threadIdx.x;
    if (i < n) o[i] = 333.0f;
}
__global__ void diag_host_k(float* o, float val) {
    if (threadIdx.x == 0 && blockIdx.x == 0) o[0] = val;
}

// ---------------- launcher ---------------------------------------------------
extern "C" void kernel_launch(void* const* d_in, const int* in_sizes, int n_in,
                              void* d_out, int out_size, void* d_ws, size_t ws_size,
                              hipStream_t stream) {
    const float* x      = (const float*)d_in[0];
    const int*   ids    = (const int*)d_in[1];
    const float* dec_w  = (const float*)d_in[2];
    const float* dec_b  = (const float*)d_in[3];
    const float* mask_t = (const float*)d_in[4];
    const float* pos    = (const float*)d_in[5];
    const float* ln1_g  = (const float*)d_in[6];
    const float* ln1_b  = (const float*)d_in[7];
    const float* in_w   = (const float*)d_in[8];
    const float* in_b   = (const float*)d_in[9];
    const float* out_w  = (const float*)d_in[10];
    const float* out_b  = (const float*)d_in[11];
    const float* ln2_g  = (const float*)d_in[12];
    const float* ln2_b  = (const float*)d_in[13];
    const float* k1_base = (const float*)d_in[14];
    const float* k1_spl  = (const float*)d_in[15];
    const float* k1_sc   = (const float*)d_in[16];
    const float* k2_base = (const float*)d_in[17];
    const float* k2_spl  = (const float*)d_in[18];
    const float* k2_sc   = (const float*)d_in[19];
    float* out = (float*)d_out;

    static const int exp_sizes[20] = {
        1597440, 16384, 196608, 512, 512, 524800, 512, 512,
        786432, 1536, 262144, 512, 512, 512,
        262144, 2097152, 262144, 131072, 1048576, 131072
    };
    int bad = -1;
    if (n_in != 20) bad = 55;
    else {
        for (int i = 0; i < 20; ++i)
            if (in_sizes[i] != exp_sizes[i]) { bad = i; break; }
        if (bad < 0 && out_size != 4194304) bad = 56;
    }
    if (bad >= 0) {
        fill_out_k<<<(out_size + 255) / 256, 256, 0, stream>>>(out, out_size);
        diag_host_k<<<1, 64, 0, stream>>>(out, ldexpf(1.0f, 30 + bad));
        return;
    }

    // ---- workspace layout (float units; ends 41,910,784 < 44,368,384) ----
    float* ws = (float*)d_ws;
    float* xres = ws;                                          // f32 [16512*512]
    __hip_bfloat16* hbufb = (__hip_bfloat16*)(ws + 8454144);   // bf16 [16512*512]
    float* R = ws + 12681216;
    float* x1 = R;                                             // f32 [4224*512]
    ushortT* xbf = (ushortT*)(R + 2162688);                    // bf16 [4224*384]
    ushortT* qkvb = (ushortT*)R;                               // bf16 [16512*1536]
    float* kan1o = R;                                          // f32 [16512*512]
    float* k2out = R + 8454144;                                // f32 [16512*256]
    ushortT* E9 = (ushortT*)(ws + 25362432);                   // bf16 [6144*4608]
    float* W = ws + 39518208;
    ushortT* dec_wb = (ushortT*)(W);
    ushortT* in_wb  = (ushortT*)(W + 98304);
    ushortT* out_wb = (ushortT*)(W + 491520);
    ushortT* W9a    = (ushortT*)(W + 622592);                  // [512*4608]
    ushortT* W9b    = (ushortT*)(W + 1802240);                 // [256*4608]
    float* zeros = W + 2392064;

    // 0. one-time converts + zeros
    zero_k<<<2, 256, 0, stream>>>(zeros, 512);
    cvt_bf16_k<<<(1597440 + 255) / 256, 256, 0, stream>>>(x, (__hip_bfloat16*)xbf, 1597440);
    cvt_bf16_k<<<(196608 + 255) / 256, 256, 0, stream>>>(dec_w, (__hip_bfloat16*)dec_wb, 196608);
    cvt_bf16_k<<<(786432 + 255) / 256, 256, 0, stream>>>(in_w, (__hip_bfloat16*)in_wb, 786432);
    cvt_bf16_k<<<(262144 + 255) / 256, 256, 0, stream>>>(out_w, (__hip_bfloat16*)out_wb, 262144);
    buildw9p<<<(262144 + 255) / 256, 256, 0, stream>>>(k1_base, k1_spl, k1_sc, W9a, 262144);
    buildw9p<<<(131072 + 255) / 256, 256, 0, stream>>>(k2_base, k2_spl, k2_sc, W9b, 131072);

    // 1. decoder embed projection -> x1 f32
    gemm_t<0><<<dim3(4, 33), 256, 0, stream>>>(xbf, dec_wb, dec_b, nullptr, x1, 4224, 512, 384);
    // 2. splice + gather + pos -> xres
    assemble_el<<<(ROWS * DMODEL + 255) / 256, 256, 0, stream>>>(x1, ids, mask_t, pos, xres);
    // 3. LN1 -> hbufb bf16
    ln_bf16<<<ROWS, 256, 0, stream>>>(xres, ln1_g, ln1_b, hbufb);
    // 4. QKV -> qkvb bf16 (x1/xbf dead)
    gemm_t<1><<<dim3(12, 129), 256, 0, stream>>>((const ushortT*)hbufb, in_wb, in_b, nullptr,
                                                 qkvb, ROWSP, 1536, 512);
    // 5. attention -> hbufb bf16 (grid: qtiles fastest for L2 reuse of K/V)
    attn_mf2<<<dim3(9, BATCH * 8), 128, 0, stream>>>(qkvb, hbufb);
    // 6. out-proj + residual -> xres f32
    gemm_t<0><<<dim3(4, 129), 256, 0, stream>>>((const ushortT*)hbufb, out_wb, out_b, xres,
                                                xres, ROWSP, 512, 512);
    // 7. LN2 in-place f32 (full-precision spline input)
    ln_f32<<<ROWS, 256, 0, stream>>>(xres, ln2_g, ln2_b, xres);

    // 8. KAN1: 3 chunks (6144,6144,4160) -> kan1o f32 (qkvb dead)
    for (int r0 = 0; r0 < ROWS; r0 += 6144) {
        int m = (ROWS - r0 < 6144) ? (ROWS - r0) : 6144;
        int mp = (m + 127) / 128 * 128;
        expand9p<<<(m * 64 + 255) / 256, 256, 0, stream>>>(xres, E9, r0, m);
        gemm_t<0><<<dim3(4, mp / 128), 256, 0, stream>>>(E9, W9a, zeros, nullptr,
                                                         kan1o + (size_t)r0 * 512, mp, 512, 4608);
    }
    // 9. KAN2 -> k2out f32
    for (int r0 = 0; r0 < ROWS; r0 += 6144) {
        int m = (ROWS - r0 < 6144) ? (ROWS - r0) : 6144;
        int mp = (m + 127) / 128 * 128;
        expand9p<<<(m * 64 + 255) / 256, 256, 0, stream>>>(kan1o, E9, r0, m);
        gemm_t<0><<<dim3(2, mp / 128), 256, 0, stream>>>(E9, W9b, zeros, nullptr,
                                                         k2out + (size_t)r0 * 256, mp, 256, 4608);
    }
    // 10. drop p==0 -> out
    drop_copy_k<<<(int)(((size_t)ROWS * 256 + 255) / 256), 256, 0, stream>>>(k2out, out);
    (void)ws_size;
}